// Round 9
// baseline (1214.839 us; speedup 1.0000x reference)
//
#include <hip/hip_runtime.h>
#include <hip/hip_bf16.h>

// GAT, H=4 heads x D=16, O=64 out channels, F=256 in features.
// Pipeline: wprep -> proj_mfma (bf16 MFMA: fc -> fsb bf16 + el/er logits,
// res -> out fp32) -> CSR build:
//   zero -> hist (atomicAdd count[dst]) -> scan(3) -> rowptr ->
//   curinit (cur[b]=rowptr[b*128]) ->
//   scatter_append (slot=atomicAdd(cur[d>>7]); sorted_pk[slot]=src<<7|dstlow)
//     -- quasi-sequential writes at 782 heads; fixes round-6's 197MB (16x)
//        write amplification from fully-random 4B scatter --
//   bucket_build2 (per-bucket LDS int-rank; writes land in bucket's own
//        ~16KB span -> L2-absorbed)
// -> agg_csr (pull-mode, one wave per dst, no fp atomics; verified 119us).
// Rounds 7-8 failed at infra level with this algorithm (no compile or
// correctness signal). This resubmission adds DEFENSIVE CLAMPS on every
// runtime-derived index (identity on correct data, bit-identical results)
// so any latent bad intermediate becomes a reported absmax error instead of
// a container-killing fault.
// Softmax max-subtraction omitted: scores O(1), exp safe in fp32,
// softmax shift-invariant -> identical result.

#define F_IN 256
#define O_OUT 64
#define NEG_SLOPE 0.2f

using frag_ab = __attribute__((ext_vector_type(8))) short;   // 8 bf16
using frag_cd = __attribute__((ext_vector_type(4))) float;   // 4 fp32

__device__ __forceinline__ float lrelu(float x) {
    return x >= 0.0f ? x : NEG_SLOPE * x;
}

__device__ __forceinline__ unsigned short f2bf(float f) {
    unsigned int u = __float_as_uint(f);
    unsigned int r = (u + 0x7fffu + ((u >> 16) & 1u)) >> 16;   // RNE
    return (unsigned short)r;
}
__device__ __forceinline__ float bflo(unsigned int p) {
    return __uint_as_float(p << 16);
}
__device__ __forceinline__ float bfhi(unsigned int p) {
    return __uint_as_float(p & 0xffff0000u);
}

// ---------------------------------------------------------------------------
// Weight prep: Wfc/Wres fp32 [64][256] -> Bf bf16 in MFMA B-frag lane order.
// ---------------------------------------------------------------------------
__global__ __launch_bounds__(256) void wprep_kernel(
    const float* __restrict__ Wfc, const float* __restrict__ Wres,
    unsigned short* __restrict__ Bf)
{
    int tid = blockIdx.x * 256 + threadIdx.x;   // 0..4095
    int ct = tid >> 9;
    int lane = tid & 63;
    int ks = (tid >> 6) & 7;
    int col = ct * 16 + (lane & 15);
    int kbase = ks * 32 + (lane >> 4) * 8;
    const float* srcW = (col < 64) ? (Wfc + (size_t)col * 256 + kbase)
                                   : (Wres + (size_t)(col - 64) * 256 + kbase);
    unsigned short* dstp = Bf + (size_t)tid * 8;
#pragma unroll
    for (int i = 0; i < 8; ++i) dstp[i] = f2bf(srcW[i]);
}

// ---------------------------------------------------------------------------
// MFMA projection: block = 256 threads (4 waves), 64 nodes.
// ---------------------------------------------------------------------------
__global__ __launch_bounds__(256) void proj_mfma_kernel(
    const float* __restrict__ feat, const unsigned short* __restrict__ Bf,
    const float* __restrict__ attn_l, const float* __restrict__ attn_r,
    unsigned short* __restrict__ fsb, float* __restrict__ el,
    float* __restrict__ er, float* __restrict__ out,
    float* __restrict__ denom_zero, int N)
{
    __shared__ __align__(16) unsigned short sA[64 * 280];   // 35840 B
    const int t = threadIdx.x;
    const int lane = t & 63;
    const int w = t >> 6;
    const int n0 = blockIdx.x * 64;
    if (n0 >= N) return;

    frag_ab bfrag[2][8];
    {
        const unsigned short* bp = Bf + (size_t)lane * 8;
#pragma unroll
        for (int j = 0; j < 2; ++j)
#pragma unroll
            for (int ks = 0; ks < 8; ++ks)
                bfrag[j][ks] = *(const frag_ab*)(bp + (size_t)((2 * w + j) * 8 + ks) * 512);
    }

    if (denom_zero && n0 * 4 + t < N * 4) denom_zero[n0 * 4 + t] = 0.0f;

    for (int i = 0; i < 8; ++i) {
        int f = i * 256 + t;
        int row = f >> 5, c8 = f & 31;
        int n = n0 + row;
        float4 v0 = make_float4(0.f, 0.f, 0.f, 0.f), v1 = v0;
        if (n < N) {
            const float4* p = (const float4*)(feat + (size_t)n * F_IN + c8 * 8);
            v0 = p[0]; v1 = p[1];
        }
        frag_ab pack;
        pack[0] = (short)f2bf(v0.x); pack[1] = (short)f2bf(v0.y);
        pack[2] = (short)f2bf(v0.z); pack[3] = (short)f2bf(v0.w);
        pack[4] = (short)f2bf(v1.x); pack[5] = (short)f2bf(v1.y);
        pack[6] = (short)f2bf(v1.z); pack[7] = (short)f2bf(v1.w);
        *(frag_ab*)(&sA[row * 280 + c8 * 8]) = pack;
    }
    __syncthreads();

    frag_cd acc[4][2];
#pragma unroll
    for (int rt = 0; rt < 4; ++rt)
#pragma unroll
        for (int j = 0; j < 2; ++j)
            acc[rt][j] = (frag_cd){0.f, 0.f, 0.f, 0.f};

#pragma unroll
    for (int ks = 0; ks < 8; ++ks) {
        frag_ab af[4];
#pragma unroll
        for (int rt = 0; rt < 4; ++rt) {
            int row = rt * 16 + (lane & 15);
            int c8 = ks * 4 + (lane >> 4);
            af[rt] = *(const frag_ab*)(&sA[row * 280 + c8 * 8]);
        }
#pragma unroll
        for (int rt = 0; rt < 4; ++rt)
#pragma unroll
            for (int j = 0; j < 2; ++j)
                acc[rt][j] = __builtin_amdgcn_mfma_f32_16x16x32_bf16(
                    af[rt], bfrag[j][ks], acc[rt][j], 0, 0, 0);
    }

    // epilogue: C/D layout col = lane&15, row = (lane>>4)*4 + reg  [m89]
    const int colq = lane & 15;
    const int quad = lane >> 4;
    if (w < 2) {
#pragma unroll
        for (int j = 0; j < 2; ++j) {
            int h = 2 * w + j;
            float al = attn_l[h * 16 + colq];
            float ar = attn_r[h * 16 + colq];
#pragma unroll
            for (int rt = 0; rt < 4; ++rt)
#pragma unroll
                for (int r = 0; r < 4; ++r) {
                    int node = n0 + rt * 16 + quad * 4 + r;
                    float v = acc[rt][j][r];
                    if (node < N) fsb[(size_t)node * O_OUT + h * 16 + colq] = f2bf(v);
                    float pl = v * al, pr = v * ar;
                    pl += __shfl_xor(pl, 1); pr += __shfl_xor(pr, 1);
                    pl += __shfl_xor(pl, 2); pr += __shfl_xor(pr, 2);
                    pl += __shfl_xor(pl, 4); pr += __shfl_xor(pr, 4);
                    pl += __shfl_xor(pl, 8); pr += __shfl_xor(pr, 8);
                    if (colq == 0 && node < N) {
                        el[(size_t)node * 4 + h] = pl;
                        er[(size_t)node * 4 + h] = pr;
                    }
                }
        }
    } else {
#pragma unroll
        for (int j = 0; j < 2; ++j) {
            int cb = 32 * (w - 2) + 16 * j;
#pragma unroll
            for (int rt = 0; rt < 4; ++rt)
#pragma unroll
                for (int r = 0; r < 4; ++r) {
                    int node = n0 + rt * 16 + quad * 4 + r;
                    if (node < N)
                        out[(size_t)node * O_OUT + cb + colq] = acc[rt][j][r];
                }
        }
    }
}

// ---------------------------------------------------------------------------
// CSR build: zero -> hist -> scan -> curinit -> append -> bucket_build2.
// ---------------------------------------------------------------------------
__global__ __launch_bounds__(256) void zero_kernel(int* __restrict__ p, int n)
{
    int i = blockIdx.x * 256 + threadIdx.x;
    if (i < n) p[i] = 0;
}

__global__ __launch_bounds__(256) void hist_kernel(
    const int* __restrict__ dst, int* __restrict__ count, int E)
{
    int e = blockIdx.x * 256 + threadIdx.x;
    if (e < E) atomicAdd(&count[dst[e]], 1);
}

__global__ __launch_bounds__(256) void curinit_kernel(
    const int* __restrict__ rowptr, int* __restrict__ cur, int R)
{
    int b = blockIdx.x * 256 + threadIdx.x;
    if (b < R) cur[b] = rowptr[b * 128];
}

// Append: quasi-sequential writes at R monotone heads (hot set ~R lines).
// slot clamped to [0,E) -- identity on correct data.
__global__ __launch_bounds__(256) void scatter_append_kernel(
    const int* __restrict__ src, const int* __restrict__ dst,
    int* __restrict__ cur, unsigned int* __restrict__ sorted_pk, int E)
{
    int e = blockIdx.x * 256 + threadIdx.x;
    if (e >= E) return;
    int d = dst[e];
    int slot = atomicAdd(&cur[d >> 7], 1);
    if ((unsigned int)slot < (unsigned int)E)
        sorted_pk[slot] = ((unsigned int)src[e] << 7) | (unsigned int)(d & 127);
}

// Localize: one block per bucket (128 dst). LDS int rank per dstlow;
// writes stay inside the bucket's own edge span (~16KB) -> L2-absorbed.
// Span + write index clamped -- identity on correct data.
__global__ __launch_bounds__(256) void bucket_build2_kernel(
    const int* __restrict__ rowptr, const unsigned int* __restrict__ sorted_pk,
    int* __restrict__ sorted_src, int N, int E)
{
    __shared__ int base[128];
    __shared__ int cur[128];
    int r = blockIdx.x, t = threadIdx.x;
    int n0 = r * 128;
    if (t < 128) {
        int node = n0 + t;
        int b = (node <= N) ? rowptr[node] : E;
        if (b < 0) b = 0; if (b > E) b = E;        // clamp
        base[t] = b;
        cur[t] = 0;
    }
    __syncthreads();
    int start = base[0];
    int hi = n0 + 128; if (hi > N) hi = N;
    int end = rowptr[hi];
    if (end < start) end = start; if (end > E) end = E;   // clamp
    for (int i = start + t; i < end; i += 256) {
        unsigned int pk = sorted_pk[i];
        int low = (int)(pk & 127u);
        int rk = atomicAdd(&cur[low], 1);
        int idx = base[low] + rk;
        if ((unsigned int)idx < (unsigned int)E)
            sorted_src[idx] = (int)(pk >> 7);
    }
}

// ---------------------------------------------------------------------------
// Scan chain (exclusive prefix sum over arbitrary n, 1024/block).
// ---------------------------------------------------------------------------
__global__ __launch_bounds__(256) void scan_block_kernel(
    const int* __restrict__ counts, int* __restrict__ outp,
    int* __restrict__ bsums, int n)
{
    int t = threadIdx.x;
    int base = blockIdx.x * 1024 + t * 4;
    int c0 = 0, c1 = 0, c2 = 0, c3 = 0;
    if (base + 3 < n) {
        int4 v = *(const int4*)(counts + base);
        c0 = v.x; c1 = v.y; c2 = v.z; c3 = v.w;
    } else {
        if (base     < n) c0 = counts[base];
        if (base + 1 < n) c1 = counts[base + 1];
        if (base + 2 < n) c2 = counts[base + 2];
        if (base + 3 < n) c3 = counts[base + 3];
    }
    int tsum = c0 + c1 + c2 + c3;
    int inc = tsum;
    int lane = t & 63, wid = t >> 6;
#pragma unroll
    for (int o = 1; o < 64; o <<= 1) {
        int v = __shfl_up(inc, o);
        if (lane >= o) inc += v;
    }
    __shared__ int wsum[4];
    if (lane == 63) wsum[wid] = inc;
    __syncthreads();
    int woff = 0;
#pragma unroll
    for (int w = 0; w < 4; ++w)
        if (w < wid) woff += wsum[w];
    int excl = woff + inc - tsum;
    int e0 = excl, e1 = excl + c0, e2 = e1 + c1, e3 = e2 + c2;
    if (base + 3 < n) {
        *(int4*)(outp + base) = make_int4(e0, e1, e2, e3);
    } else {
        if (base     < n) outp[base]     = e0;
        if (base + 1 < n) outp[base + 1] = e1;
        if (base + 2 < n) outp[base + 2] = e2;
        if (base + 3 < n) outp[base + 3] = e3;
    }
    if (t == 255) bsums[blockIdx.x] = wsum[0] + wsum[1] + wsum[2] + wsum[3];
}

__global__ void scan_bsums_kernel(int* __restrict__ bsums, int nb)
{
    int lane = threadIdx.x;   // 64 threads
    int carry = 0;
    for (int c = 0; c * 64 < nb; ++c) {
        int i = c * 64 + lane;
        int v = (i < nb) ? bsums[i] : 0;
        int inc = v;
#pragma unroll
        for (int o = 1; o < 64; o <<= 1) {
            int u = __shfl_up(inc, o);
            if (lane >= o) inc += u;
        }
        if (i < nb) bsums[i] = carry + inc - v;
        carry += __shfl(inc, 63);
    }
}

__global__ __launch_bounds__(256) void scan_final_kernel(
    int* __restrict__ outp, const int* __restrict__ bsums, int n, int total)
{
    int i = blockIdx.x * 256 + threadIdx.x;
    if (i < n) outp[i] = outp[i] + bsums[i >> 10];
    if (i == 0) outp[n] = total;   // outp must have n+1 capacity
}

// ---------------------------------------------------------------------------
// CSR aggregation: one wave per dst node. 2 edges/iter (half-waves), each
// lane owns a bf16x2 channel pair; 4 pairs unrolled. (Verified round-0.)
// k-range and gathered s clamped -- identity on correct data.
// ---------------------------------------------------------------------------
__global__ __launch_bounds__(256) void agg_csr_kernel(
    const int* __restrict__ rowptr, const int* __restrict__ srt,
    const unsigned short* __restrict__ fsb, const float* __restrict__ el,
    const float* __restrict__ er, float* __restrict__ out, int N)
{
    int d = blockIdx.x * 4 + (threadIdx.x >> 6);
    if (d >= N) return;
    const int lane = threadIdx.x & 63;
    const int half = lane >> 5;
    const int c = lane & 31;           // channels 2c, 2c+1
    const int h = c >> 3;
    int k0 = rowptr[d], k1 = rowptr[d + 1];
    if (k0 < 0) k0 = 0;
    if (k1 < k0) k1 = k0;              // clamp (identity on correct data)
    const int smax = N - 1;
    const float erh = er[(size_t)d * 4 + h];
    float a0 = 0.f, a1 = 0.f, den = 0.f;

    int kb = k0;
    for (; kb + 8 <= k1; kb += 8) {
        int s0 = srt[kb + half];
        int s1 = srt[kb + 2 + half];
        int s2 = srt[kb + 4 + half];
        int s3 = srt[kb + 6 + half];
        s0 = ((unsigned)s0 <= (unsigned)smax) ? s0 : 0;
        s1 = ((unsigned)s1 <= (unsigned)smax) ? s1 : 0;
        s2 = ((unsigned)s2 <= (unsigned)smax) ? s2 : 0;
        s3 = ((unsigned)s3 <= (unsigned)smax) ? s3 : 0;
        float e0 = el[(size_t)s0 * 4 + h];
        float e1 = el[(size_t)s1 * 4 + h];
        float e2 = el[(size_t)s2 * 4 + h];
        float e3 = el[(size_t)s3 * 4 + h];
        unsigned int f0 = *(const unsigned int*)(fsb + (size_t)s0 * O_OUT + 2 * c);
        unsigned int f1 = *(const unsigned int*)(fsb + (size_t)s1 * O_OUT + 2 * c);
        unsigned int f2 = *(const unsigned int*)(fsb + (size_t)s2 * O_OUT + 2 * c);
        unsigned int f3 = *(const unsigned int*)(fsb + (size_t)s3 * O_OUT + 2 * c);
        float w0 = __expf(lrelu(e0 + erh));
        float w1 = __expf(lrelu(e1 + erh));
        float w2 = __expf(lrelu(e2 + erh));
        float w3 = __expf(lrelu(e3 + erh));
        a0 += w0 * bflo(f0); a1 += w0 * bfhi(f0); den += w0;
        a0 += w1 * bflo(f1); a1 += w1 * bfhi(f1); den += w1;
        a0 += w2 * bflo(f2); a1 += w2 * bfhi(f2); den += w2;
        a0 += w3 * bflo(f3); a1 += w3 * bfhi(f3); den += w3;
    }
    for (; kb < k1; kb += 2) {
        int ki = kb + half;
        if (ki < k1) {
            int s = srt[ki];
            s = ((unsigned)s <= (unsigned)smax) ? s : 0;
            float w = __expf(lrelu(el[(size_t)s * 4 + h] + erh));
            unsigned int f = *(const unsigned int*)(fsb + (size_t)s * O_OUT + 2 * c);
            a0 += w * bflo(f); a1 += w * bfhi(f); den += w;
        }
    }
    a0 += __shfl_xor(a0, 32);
    a1 += __shfl_xor(a1, 32);
    den += __shfl_xor(den, 32);
    if (half == 0) {
        float inv = 1.0f / fmaxf(den, 1e-20f);
        float2* po = (float2*)(out + (size_t)d * O_OUT + 2 * c);
        float2 o = *po;
        o.x += a0 * inv;
        o.y += a1 * inv;
        *po = o;
    }
}

// ---------------------------------------------------------------------------
// Fallback path (small ws): no-max softmax, atomics, bf16 fs.
// ---------------------------------------------------------------------------
__global__ __launch_bounds__(256) void edge_sum_kernel(
    const int* __restrict__ src, const int* __restrict__ dst,
    const float* __restrict__ el, const float* __restrict__ er,
    float* __restrict__ denom, int E)
{
    int e = blockIdx.x * 256 + threadIdx.x;
    if (e >= E) return;
    int s = src[e], d = dst[e];
    float4 l4 = ((const float4*)el)[s];
    float4 r4 = ((const float4*)er)[d];
    unsafeAtomicAdd(&denom[(size_t)d * 4 + 0], __expf(lrelu(l4.x + r4.x)));
    unsafeAtomicAdd(&denom[(size_t)d * 4 + 1], __expf(lrelu(l4.y + r4.y)));
    unsafeAtomicAdd(&denom[(size_t)d * 4 + 2], __expf(lrelu(l4.z + r4.z)));
    unsafeAtomicAdd(&denom[(size_t)d * 4 + 3], __expf(lrelu(l4.w + r4.w)));
}

__global__ __launch_bounds__(256) void agg_atomic_kernel(
    const int* __restrict__ src, const int* __restrict__ dst,
    const unsigned short* __restrict__ fsb, const float* __restrict__ el,
    const float* __restrict__ er, const float* __restrict__ denom,
    float* __restrict__ out, int E)
{
    const int lane = threadIdx.x & 63;
    const int wid = threadIdx.x >> 6;
    int e = blockIdx.x * 4 + wid;
    if (e >= E) return;
    int s = src[e], d = dst[e];
    int h = lane >> 4;
    float v = __expf(lrelu(el[(size_t)s * 4 + h] + er[(size_t)d * 4 + h]));
    float alpha = v / fmaxf(denom[(size_t)d * 4 + h], 1e-20f);
    float fval = __uint_as_float(((unsigned int)fsb[(size_t)s * O_OUT + lane]) << 16);
    unsafeAtomicAdd(&out[(size_t)d * O_OUT + lane], alpha * fval);
}

extern "C" void kernel_launch(void* const* d_in, const int* in_sizes, int n_in,
                              void* d_out, int out_size, void* d_ws, size_t ws_size,
                              hipStream_t stream) {
    const float* feat   = (const float*)d_in[0];
    const float* Wfc    = (const float*)d_in[1];
    const float* attn_l = (const float*)d_in[2];
    const float* attn_r = (const float*)d_in[3];
    const float* Wres   = (const float*)d_in[4];
    const int*   src    = (const int*)d_in[5];
    const int*   dst    = (const int*)d_in[6];

    const int N = in_sizes[0] / F_IN;     // 100000
    const int E = in_sizes[5];            // 3200000
    float* out = (float*)d_out;

    const int R = (N + 127) >> 7;         // buckets of 128 nodes

    // layout: el | er | Bf | count[N] | rowptr[N+4] | bsums[1024] | cur[R+8] |
    //         sorted_pk[E] | sorted_src[E] | fsb
    float* el     = (float*)d_ws;
    float* er     = el + (size_t)N * 4;
    unsigned short* Bf = (unsigned short*)(er + (size_t)N * 4);
    int*   count  = (int*)(Bf + 32768);
    int*   rowptr = count + N;
    int*   bsums  = rowptr + N + 4;
    int*   cur    = bsums + 1024;
    unsigned int* sorted_pk = (unsigned int*)(cur + R + 8);
    int*   sorted_src = (int*)(sorted_pk + E);
    unsigned short* fsb = (unsigned short*)(sorted_src + E);
    size_t need_main = (size_t)((char*)(fsb + (size_t)N * O_OUT) - (char*)d_ws);

    int nproj = (N + 63) / 64;
    int nsb = (N + 1023) / 1024;          // scan blocks over count[N]

    if (ws_size >= need_main && nsb <= 1024) {
        wprep_kernel<<<16, 256, 0, stream>>>(Wfc, Wres, Bf);
        proj_mfma_kernel<<<nproj, 256, 0, stream>>>(
            feat, Bf, attn_l, attn_r, fsb, el, er, out, nullptr, N);
        zero_kernel<<<(N + 255) / 256, 256, 0, stream>>>(count, N);
        hist_kernel<<<(E + 255) / 256, 256, 0, stream>>>(dst, count, E);
        scan_block_kernel<<<nsb, 256, 0, stream>>>(count, rowptr, bsums, N);
        scan_bsums_kernel<<<1, 64, 0, stream>>>(bsums, nsb);
        scan_final_kernel<<<(N + 255) / 256, 256, 0, stream>>>(rowptr, bsums, N, E);
        curinit_kernel<<<(R + 255) / 256, 256, 0, stream>>>(rowptr, cur, R);
        scatter_append_kernel<<<(E + 255) / 256, 256, 0, stream>>>(
            src, dst, cur, sorted_pk, E);
        bucket_build2_kernel<<<R, 256, 0, stream>>>(
            rowptr, sorted_pk, sorted_src, N, E);
        agg_csr_kernel<<<(N + 3) / 4, 256, 0, stream>>>(
            rowptr, sorted_src, fsb, el, er, out, N);
    } else {
        // fallback: denom overlays count region; fsb right after denom
        float* denom = (float*)count;                 // [N*4]
        unsigned short* fsb2 = (unsigned short*)(denom + (size_t)N * 4);
        wprep_kernel<<<16, 256, 0, stream>>>(Wfc, Wres, Bf);
        proj_mfma_kernel<<<nproj, 256, 0, stream>>>(
            feat, Bf, attn_l, attn_r, fsb2, el, er, out, denom, N);
        edge_sum_kernel<<<(E + 255) / 256, 256, 0, stream>>>(src, dst, el, er, denom, E);
        agg_atomic_kernel<<<(E + 3) / 4, 256, 0, stream>>>(
            src, dst, fsb2, el, er, denom, out, E);
    }
}

// Round 10
// 455.639 us; speedup vs baseline: 2.6662x; 2.6662x over previous
//
#include <hip/hip_runtime.h>
#include <hip/hip_bf16.h>

// GAT, H=4 heads x D=16, O=64 out channels, F=256 in features.
// Pipeline (round-0 verified structure, bucket_build MERGED into agg):
// wprep -> proj_mfma (bf16 MFMA: fc -> fsb bf16 + el/er logits, res -> out
// fp32) -> bucket_count (LDS hist over dst>>7) -> scan(3) over histT ->
// bucket_scatter (LDS-rank, packed (src<<7|dstlow) runs per (bin,block)) ->
// agg_bucket (per-bucket: LDS hist/scan/bin of the contiguous pk run, then
//             agg_csr's 64-lane gather loop reading src from LDS).
// Eliminates bucket_build's 25.6MB sorted_src round-trip (~60us).
// Measured ledger: agg_csr 119us | r0 total 455us | global hist+scatter
// ~410us (r6) | 782-head append 747us (r9) | LDS fp-atomic agg 1450us (r2-5).
// NO global atomics anywhere in the main path.
// Softmax max-subtraction omitted: scores O(1), exp safe in fp32,
// softmax shift-invariant -> identical result.

#define F_IN 256
#define O_OUT 64
#define NEG_SLOPE 0.2f
#define CHUNK 16384          // edges per block in bucket passes (r0-proven)
#define RMAX 2048            // max buckets supported by LDS hist

using frag_ab = __attribute__((ext_vector_type(8))) short;   // 8 bf16
using frag_cd = __attribute__((ext_vector_type(4))) float;   // 4 fp32

__device__ __forceinline__ float lrelu(float x) {
    return x >= 0.0f ? x : NEG_SLOPE * x;
}

__device__ __forceinline__ unsigned short f2bf(float f) {
    unsigned int u = __float_as_uint(f);
    unsigned int r = (u + 0x7fffu + ((u >> 16) & 1u)) >> 16;   // RNE
    return (unsigned short)r;
}
__device__ __forceinline__ float bflo(unsigned int p) {
    return __uint_as_float(p << 16);
}
__device__ __forceinline__ float bfhi(unsigned int p) {
    return __uint_as_float(p & 0xffff0000u);
}

// ---------------------------------------------------------------------------
// Weight prep: Wfc/Wres fp32 [64][256] -> Bf bf16 in MFMA B-frag lane order.
// ---------------------------------------------------------------------------
__global__ __launch_bounds__(256) void wprep_kernel(
    const float* __restrict__ Wfc, const float* __restrict__ Wres,
    unsigned short* __restrict__ Bf)
{
    int tid = blockIdx.x * 256 + threadIdx.x;   // 0..4095
    int ct = tid >> 9;
    int lane = tid & 63;
    int ks = (tid >> 6) & 7;
    int col = ct * 16 + (lane & 15);
    int kbase = ks * 32 + (lane >> 4) * 8;
    const float* srcW = (col < 64) ? (Wfc + (size_t)col * 256 + kbase)
                                   : (Wres + (size_t)(col - 64) * 256 + kbase);
    unsigned short* dstp = Bf + (size_t)tid * 8;
#pragma unroll
    for (int i = 0; i < 8; ++i) dstp[i] = f2bf(srcW[i]);
}

// ---------------------------------------------------------------------------
// MFMA projection: block = 256 threads (4 waves), 64 nodes.
// ---------------------------------------------------------------------------
__global__ __launch_bounds__(256) void proj_mfma_kernel(
    const float* __restrict__ feat, const unsigned short* __restrict__ Bf,
    const float* __restrict__ attn_l, const float* __restrict__ attn_r,
    unsigned short* __restrict__ fsb, float* __restrict__ el,
    float* __restrict__ er, float* __restrict__ out,
    float* __restrict__ denom_zero, int N)
{
    __shared__ __align__(16) unsigned short sA[64 * 280];   // 35840 B
    const int t = threadIdx.x;
    const int lane = t & 63;
    const int w = t >> 6;
    const int n0 = blockIdx.x * 64;
    if (n0 >= N) return;

    frag_ab bfrag[2][8];
    {
        const unsigned short* bp = Bf + (size_t)lane * 8;
#pragma unroll
        for (int j = 0; j < 2; ++j)
#pragma unroll
            for (int ks = 0; ks < 8; ++ks)
                bfrag[j][ks] = *(const frag_ab*)(bp + (size_t)((2 * w + j) * 8 + ks) * 512);
    }

    if (denom_zero && n0 * 4 + t < N * 4) denom_zero[n0 * 4 + t] = 0.0f;

    for (int i = 0; i < 8; ++i) {
        int f = i * 256 + t;
        int row = f >> 5, c8 = f & 31;
        int n = n0 + row;
        float4 v0 = make_float4(0.f, 0.f, 0.f, 0.f), v1 = v0;
        if (n < N) {
            const float4* p = (const float4*)(feat + (size_t)n * F_IN + c8 * 8);
            v0 = p[0]; v1 = p[1];
        }
        frag_ab pack;
        pack[0] = (short)f2bf(v0.x); pack[1] = (short)f2bf(v0.y);
        pack[2] = (short)f2bf(v0.z); pack[3] = (short)f2bf(v0.w);
        pack[4] = (short)f2bf(v1.x); pack[5] = (short)f2bf(v1.y);
        pack[6] = (short)f2bf(v1.z); pack[7] = (short)f2bf(v1.w);
        *(frag_ab*)(&sA[row * 280 + c8 * 8]) = pack;
    }
    __syncthreads();

    frag_cd acc[4][2];
#pragma unroll
    for (int rt = 0; rt < 4; ++rt)
#pragma unroll
        for (int j = 0; j < 2; ++j)
            acc[rt][j] = (frag_cd){0.f, 0.f, 0.f, 0.f};

#pragma unroll
    for (int ks = 0; ks < 8; ++ks) {
        frag_ab af[4];
#pragma unroll
        for (int rt = 0; rt < 4; ++rt) {
            int row = rt * 16 + (lane & 15);
            int c8 = ks * 4 + (lane >> 4);
            af[rt] = *(const frag_ab*)(&sA[row * 280 + c8 * 8]);
        }
#pragma unroll
        for (int rt = 0; rt < 4; ++rt)
#pragma unroll
            for (int j = 0; j < 2; ++j)
                acc[rt][j] = __builtin_amdgcn_mfma_f32_16x16x32_bf16(
                    af[rt], bfrag[j][ks], acc[rt][j], 0, 0, 0);
    }

    // epilogue: C/D layout col = lane&15, row = (lane>>4)*4 + reg  [m89]
    const int colq = lane & 15;
    const int quad = lane >> 4;
    if (w < 2) {
#pragma unroll
        for (int j = 0; j < 2; ++j) {
            int h = 2 * w + j;
            float al = attn_l[h * 16 + colq];
            float ar = attn_r[h * 16 + colq];
#pragma unroll
            for (int rt = 0; rt < 4; ++rt)
#pragma unroll
                for (int r = 0; r < 4; ++r) {
                    int node = n0 + rt * 16 + quad * 4 + r;
                    float v = acc[rt][j][r];
                    if (node < N) fsb[(size_t)node * O_OUT + h * 16 + colq] = f2bf(v);
                    float pl = v * al, pr = v * ar;
                    pl += __shfl_xor(pl, 1); pr += __shfl_xor(pr, 1);
                    pl += __shfl_xor(pl, 2); pr += __shfl_xor(pr, 2);
                    pl += __shfl_xor(pl, 4); pr += __shfl_xor(pr, 4);
                    pl += __shfl_xor(pl, 8); pr += __shfl_xor(pr, 8);
                    if (colq == 0 && node < N) {
                        el[(size_t)node * 4 + h] = pl;
                        er[(size_t)node * 4 + h] = pr;
                    }
                }
        }
    } else {
#pragma unroll
        for (int j = 0; j < 2; ++j) {
            int cb = 32 * (w - 2) + 16 * j;
#pragma unroll
            for (int rt = 0; rt < 4; ++rt)
#pragma unroll
                for (int r = 0; r < 4; ++r) {
                    int node = n0 + rt * 16 + quad * 4 + r;
                    if (node < N)
                        out[(size_t)node * O_OUT + cb + colq] = acc[rt][j][r];
                }
        }
    }
}

// ---------------------------------------------------------------------------
// Bucket pass A: per-block LDS histogram of dst>>7 -> histT[bin*B + b].
// ---------------------------------------------------------------------------
__global__ __launch_bounds__(256) void bucket_count_kernel(
    const int* __restrict__ dst, int* __restrict__ histT, int E, int B, int R)
{
    __shared__ int h[RMAX];
    int b = blockIdx.x, t = threadIdx.x;
    for (int i = t; i < R; i += 256) h[i] = 0;
    __syncthreads();
    int base = b * CHUNK;
    for (int i = t; i < CHUNK; i += 256) {
        int e = base + i;
        if (e < E) atomicAdd(&h[dst[e] >> 7], 1);
    }
    __syncthreads();
    for (int i = t; i < R; i += 256) histT[(size_t)i * B + b] = h[i];
}

// ---------------------------------------------------------------------------
// Scan chain (exclusive prefix sum over arbitrary n, 1024/block).
// ---------------------------------------------------------------------------
__global__ __launch_bounds__(256) void scan_block_kernel(
    const int* __restrict__ counts, int* __restrict__ outp,
    int* __restrict__ bsums, int n)
{
    int t = threadIdx.x;
    int base = blockIdx.x * 1024 + t * 4;
    int c0 = 0, c1 = 0, c2 = 0, c3 = 0;
    if (base + 3 < n) {
        int4 v = *(const int4*)(counts + base);
        c0 = v.x; c1 = v.y; c2 = v.z; c3 = v.w;
    } else {
        if (base     < n) c0 = counts[base];
        if (base + 1 < n) c1 = counts[base + 1];
        if (base + 2 < n) c2 = counts[base + 2];
        if (base + 3 < n) c3 = counts[base + 3];
    }
    int tsum = c0 + c1 + c2 + c3;
    int inc = tsum;
    int lane = t & 63, wid = t >> 6;
#pragma unroll
    for (int o = 1; o < 64; o <<= 1) {
        int v = __shfl_up(inc, o);
        if (lane >= o) inc += v;
    }
    __shared__ int wsum[4];
    if (lane == 63) wsum[wid] = inc;
    __syncthreads();
    int woff = 0;
#pragma unroll
    for (int w = 0; w < 4; ++w)
        if (w < wid) woff += wsum[w];
    int excl = woff + inc - tsum;
    int e0 = excl, e1 = excl + c0, e2 = e1 + c1, e3 = e2 + c2;
    if (base + 3 < n) {
        *(int4*)(outp + base) = make_int4(e0, e1, e2, e3);
    } else {
        if (base     < n) outp[base]     = e0;
        if (base + 1 < n) outp[base + 1] = e1;
        if (base + 2 < n) outp[base + 2] = e2;
        if (base + 3 < n) outp[base + 3] = e3;
    }
    if (t == 255) bsums[blockIdx.x] = wsum[0] + wsum[1] + wsum[2] + wsum[3];
}

__global__ void scan_bsums_kernel(int* __restrict__ bsums, int nb)
{
    int lane = threadIdx.x;   // 64 threads
    int carry = 0;
    for (int c = 0; c * 64 < nb; ++c) {
        int i = c * 64 + lane;
        int v = (i < nb) ? bsums[i] : 0;
        int inc = v;
#pragma unroll
        for (int o = 1; o < 64; o <<= 1) {
            int u = __shfl_up(inc, o);
            if (lane >= o) inc += u;
        }
        if (i < nb) bsums[i] = carry + inc - v;
        carry += __shfl(inc, 63);
    }
}

__global__ __launch_bounds__(256) void scan_final_kernel(
    int* __restrict__ outp, const int* __restrict__ bsums, int n, int total)
{
    int i = blockIdx.x * 256 + threadIdx.x;
    if (i < n) outp[i] = outp[i] + bsums[i >> 10];
    if (i == 0) outp[n] = total;   // outp must have n+1 capacity
}

// ---------------------------------------------------------------------------
// Bucket pass C: LDS-atomic local rank; write packed (src<<7)|dstlow to
// sorted_pk at histS[bin*B+b] + rank. Per-bucket runs are contiguous.
// ---------------------------------------------------------------------------
__global__ __launch_bounds__(256) void bucket_scatter_kernel(
    const int* __restrict__ src, const int* __restrict__ dst,
    const int* __restrict__ histS, unsigned int* __restrict__ sorted_pk,
    int E, int B, int R)
{
    __shared__ int h[RMAX];
    __shared__ int basebin[RMAX];
    int b = blockIdx.x, t = threadIdx.x;
    for (int i = t; i < R; i += 256) {
        h[i] = 0;
        basebin[i] = histS[(size_t)i * B + b];
    }
    __syncthreads();
    int base = b * CHUNK;
    for (int i = t; i < CHUNK; i += 256) {
        int e = base + i;
        if (e < E) {
            int d = dst[e];
            int bin = d >> 7;
            int rk = atomicAdd(&h[bin], 1);
            sorted_pk[basebin[bin] + rk] =
                ((unsigned int)src[e] << 7) | (unsigned int)(d & 127);
        }
    }
}

// ---------------------------------------------------------------------------
// Merged build+agg: one block per bucket (128 dst, 512 threads / 8 waves).
// LDS hist/scan/bin of the bucket's contiguous sorted_pk run (bucket_build's
// verified logic, target = LDS instead of global), then each wave runs
// agg_csr's verified 64-lane gather loop on 16 dst, src read from LDS.
// ---------------------------------------------------------------------------
__global__ __launch_bounds__(512) void agg_bucket_kernel(
    const int* __restrict__ histS, const unsigned int* __restrict__ sorted_pk,
    const unsigned short* __restrict__ fsb, const float* __restrict__ el,
    const float* __restrict__ er, float* __restrict__ out,
    int N, int E, int B, int R)
{
    __shared__ int buf2[8192];                  // binned src values, 32 KiB
    __shared__ int hist[128], scn[128], cur[128];
    const int r = blockIdx.x;
    const int t = threadIdx.x;
    int start = histS[(size_t)r * B];
    int end = (r + 1 < R) ? histS[(size_t)(r + 1) * B] : E;
    if (start < 0) start = 0;
    if (end < start) end = start;
    if (end > E) end = E;                       // clamps: identity on correct data
    const int cnt = end - start;

    if (t < 128) { hist[t] = 0; cur[t] = 0; }
    __syncthreads();
    // pass 1: histogram over dstlow (coalesced global pk read, LDS int atomics)
    for (int i = t; i < cnt; i += 512)
        atomicAdd(&hist[sorted_pk[start + i] & 127], 1);
    __syncthreads();
    if (t < 128) scn[t] = hist[t];
    __syncthreads();
    for (int o = 1; o < 128; o <<= 1) {
        int v = 0;
        if (t < 128 && t >= o) v = scn[t - o];
        __syncthreads();
        if (t < 128) scn[t] += v;
        __syncthreads();
    }
    // pass 2: bin src values into LDS (scn inclusive; offset = scn - hist)
    const bool use_lds = (cnt <= 8192);
    if (use_lds) {
        for (int i = t; i < cnt; i += 512) {
            unsigned int pk = sorted_pk[start + i];
            int low = (int)(pk & 127u);
            int rk = atomicAdd(&cur[low], 1);
            buf2[(scn[low] - hist[low]) + rk] = (int)(pk >> 7);
        }
    }
    __syncthreads();

    // agg: wave w handles dst r*128 + w*16 + j, j=0..15 (agg_csr loop body)
    const int lane = t & 63;
    const int w = t >> 6;              // 0..7
    const int half = lane >> 5;
    const int c = lane & 31;           // channels 2c, 2c+1
    const int h = c >> 3;
    for (int j = 0; j < 16; ++j) {
        int dl = w * 16 + j;
        int d = r * 128 + dl;
        if (d >= N) break;             // dl increasing -> all later invalid too
        const int k0 = scn[dl] - hist[dl];
        const int k1 = scn[dl];
        const float erh = er[(size_t)d * 4 + h];
        float a0 = 0.f, a1 = 0.f, den = 0.f;
        if (use_lds) {
            int kb = k0;
            for (; kb + 8 <= k1; kb += 8) {
                int s0 = buf2[kb + half];
                int s1 = buf2[kb + 2 + half];
                int s2 = buf2[kb + 4 + half];
                int s3 = buf2[kb + 6 + half];
                float e0 = el[(size_t)s0 * 4 + h];
                float e1 = el[(size_t)s1 * 4 + h];
                float e2 = el[(size_t)s2 * 4 + h];
                float e3 = el[(size_t)s3 * 4 + h];
                unsigned int f0 = *(const unsigned int*)(fsb + (size_t)s0 * O_OUT + 2 * c);
                unsigned int f1 = *(const unsigned int*)(fsb + (size_t)s1 * O_OUT + 2 * c);
                unsigned int f2 = *(const unsigned int*)(fsb + (size_t)s2 * O_OUT + 2 * c);
                unsigned int f3 = *(const unsigned int*)(fsb + (size_t)s3 * O_OUT + 2 * c);
                float w0 = __expf(lrelu(e0 + erh));
                float w1 = __expf(lrelu(e1 + erh));
                float w2 = __expf(lrelu(e2 + erh));
                float w3 = __expf(lrelu(e3 + erh));
                a0 += w0 * bflo(f0); a1 += w0 * bfhi(f0); den += w0;
                a0 += w1 * bflo(f1); a1 += w1 * bfhi(f1); den += w1;
                a0 += w2 * bflo(f2); a1 += w2 * bfhi(f2); den += w2;
                a0 += w3 * bflo(f3); a1 += w3 * bfhi(f3); den += w3;
            }
            for (; kb < k1; kb += 2) {
                int ki = kb + half;
                if (ki < k1) {
                    int s = buf2[ki];
                    float wv = __expf(lrelu(el[(size_t)s * 4 + h] + erh));
                    unsigned int f = *(const unsigned int*)(fsb + (size_t)s * O_OUT + 2 * c);
                    a0 += wv * bflo(f); a1 += wv * bfhi(f); den += wv;
                }
            }
        } else {
            // fallback (cnt > 8192, not expected at bench sizes): filter scan
            for (int i2 = 0; i2 < cnt; i2 += 2) {
                int ki = i2 + half;
                if (ki < cnt) {
                    unsigned int pk = sorted_pk[start + ki];
                    if ((int)(pk & 127u) == dl) {
                        int s = (int)(pk >> 7);
                        float wv = __expf(lrelu(el[(size_t)s * 4 + h] + erh));
                        unsigned int f = *(const unsigned int*)(fsb + (size_t)s * O_OUT + 2 * c);
                        a0 += wv * bflo(f); a1 += wv * bfhi(f); den += wv;
                    }
                }
            }
        }
        a0 += __shfl_xor(a0, 32);
        a1 += __shfl_xor(a1, 32);
        den += __shfl_xor(den, 32);
        if (half == 0) {
            float inv = 1.0f / fmaxf(den, 1e-20f);
            float2* po = (float2*)(out + (size_t)d * O_OUT + 2 * c);
            float2 o = *po;
            o.x += a0 * inv;
            o.y += a1 * inv;
            *po = o;
        }
    }
}

// ---------------------------------------------------------------------------
// Fallback path (small ws): no-max softmax, atomics, bf16 fs.
// ---------------------------------------------------------------------------
__global__ __launch_bounds__(256) void edge_sum_kernel(
    const int* __restrict__ src, const int* __restrict__ dst,
    const float* __restrict__ el, const float* __restrict__ er,
    float* __restrict__ denom, int E)
{
    int e = blockIdx.x * 256 + threadIdx.x;
    if (e >= E) return;
    int s = src[e], d = dst[e];
    float4 l4 = ((const float4*)el)[s];
    float4 r4 = ((const float4*)er)[d];
    unsafeAtomicAdd(&denom[(size_t)d * 4 + 0], __expf(lrelu(l4.x + r4.x)));
    unsafeAtomicAdd(&denom[(size_t)d * 4 + 1], __expf(lrelu(l4.y + r4.y)));
    unsafeAtomicAdd(&denom[(size_t)d * 4 + 2], __expf(lrelu(l4.z + r4.z)));
    unsafeAtomicAdd(&denom[(size_t)d * 4 + 3], __expf(lrelu(l4.w + r4.w)));
}

__global__ __launch_bounds__(256) void agg_atomic_kernel(
    const int* __restrict__ src, const int* __restrict__ dst,
    const unsigned short* __restrict__ fsb, const float* __restrict__ el,
    const float* __restrict__ er, const float* __restrict__ denom,
    float* __restrict__ out, int E)
{
    const int lane = threadIdx.x & 63;
    const int wid = threadIdx.x >> 6;
    int e = blockIdx.x * 4 + wid;
    if (e >= E) return;
    int s = src[e], d = dst[e];
    int h = lane >> 4;
    float v = __expf(lrelu(el[(size_t)s * 4 + h] + er[(size_t)d * 4 + h]));
    float alpha = v / fmaxf(denom[(size_t)d * 4 + h], 1e-20f);
    float fval = __uint_as_float(((unsigned int)fsb[(size_t)s * O_OUT + lane]) << 16);
    unsafeAtomicAdd(&out[(size_t)d * O_OUT + lane], alpha * fval);
}

extern "C" void kernel_launch(void* const* d_in, const int* in_sizes, int n_in,
                              void* d_out, int out_size, void* d_ws, size_t ws_size,
                              hipStream_t stream) {
    const float* feat   = (const float*)d_in[0];
    const float* Wfc    = (const float*)d_in[1];
    const float* attn_l = (const float*)d_in[2];
    const float* attn_r = (const float*)d_in[3];
    const float* Wres   = (const float*)d_in[4];
    const int*   src    = (const int*)d_in[5];
    const int*   dst    = (const int*)d_in[6];

    const int N = in_sizes[0] / F_IN;     // 100000
    const int E = in_sizes[5];            // 3200000
    float* out = (float*)d_out;

    const int R = (N + 127) >> 7;                 // buckets of 128 nodes
    const int B = (E + CHUNK - 1) / CHUNK;        // blocks in bucket passes
    const int nRB = R * B;
    const int nsb = (nRB + 1023) / 1024;

    // layout: el | er | Bf | histT[nRB] | histS[nRB+8] | bsums[1024] |
    //         sorted_pk[E] | fsb
    float* el     = (float*)d_ws;
    float* er     = el + (size_t)N * 4;
    unsigned short* Bf = (unsigned short*)(er + (size_t)N * 4);
    int*   histT  = (int*)(Bf + 32768);
    int*   histS  = histT + nRB;
    int*   bsums  = histS + nRB + 8;
    unsigned int* sorted_pk = (unsigned int*)(bsums + 1024);
    unsigned short* fsb = (unsigned short*)(sorted_pk + E);
    size_t need_main = (size_t)((char*)(fsb + (size_t)N * O_OUT) - (char*)d_ws);

    int nproj = (N + 63) / 64;

    if (ws_size >= need_main && R <= RMAX && nsb <= 1024) {
        wprep_kernel<<<16, 256, 0, stream>>>(Wfc, Wres, Bf);
        proj_mfma_kernel<<<nproj, 256, 0, stream>>>(
            feat, Bf, attn_l, attn_r, fsb, el, er, out, nullptr, N);
        bucket_count_kernel<<<B, 256, 0, stream>>>(dst, histT, E, B, R);
        scan_block_kernel<<<nsb, 256, 0, stream>>>(histT, histS, bsums, nRB);
        scan_bsums_kernel<<<1, 64, 0, stream>>>(bsums, nsb);
        scan_final_kernel<<<(nRB + 255) / 256, 256, 0, stream>>>(histS, bsums, nRB, E);
        bucket_scatter_kernel<<<B, 256, 0, stream>>>(src, dst, histS, sorted_pk, E, B, R);
        agg_bucket_kernel<<<R, 512, 0, stream>>>(
            histS, sorted_pk, fsb, el, er, out, N, E, B, R);
    } else {
        // fallback: denom overlays histT region; fsb right after denom
        float* denom = (float*)histT;                 // [N*4]
        unsigned short* fsb2 = (unsigned short*)(denom + (size_t)N * 4);
        wprep_kernel<<<16, 256, 0, stream>>>(Wfc, Wres, Bf);
        proj_mfma_kernel<<<nproj, 256, 0, stream>>>(
            feat, Bf, attn_l, attn_r, fsb2, el, er, out, denom, N);
        edge_sum_kernel<<<(E + 255) / 256, 256, 0, stream>>>(src, dst, el, er, denom, E);
        agg_atomic_kernel<<<(E + 3) / 4, 256, 0, stream>>>(
            src, dst, fsb2, el, er, denom, out, E);
    }
}

// Round 11
// 427.670 us; speedup vs baseline: 2.8406x; 1.0654x over previous
//
#include <hip/hip_runtime.h>
#include <hip/hip_bf16.h>

// GAT, H=4 heads x D=16, O=64 out channels, F=256 in features.
// Pipeline (round-10 structure, CHUNK 16384 -> 4096):
// wprep -> proj_mfma (bf16 MFMA: fc -> fsb bf16 + el/er logits, res -> out
// fp32) -> bucket_count (LDS hist over dst>>7) -> scan(3) over histT ->
// bucket_scatter (LDS-rank, packed (src<<7|dstlow) runs per (bin,block)) ->
// agg_bucket (per-bucket: LDS hist/scan/bin of the contiguous pk run, then
//             agg_csr's 64-lane gather loop reading src from LDS).
// CHUNK=4096: 782 blocks (~3/CU) vs 196 (~1/CU) -- r2-vs-r10 differencing
// on the identical kernel set shows -39us on the bucket passes.
// Measured ledger: agg_csr 119.5 | agg_bucket 144.6 (= csr+build, neutral) |
// r0 total 455.3 | global hist+scatter ~410 (r6) | 782-head append 747 (r9) |
// LDS fp-atomic agg 1450 (r2-5).
// NO global atomics anywhere in the main path.
// Softmax max-subtraction omitted: scores O(1), exp safe in fp32,
// softmax shift-invariant -> identical result.

#define F_IN 256
#define O_OUT 64
#define NEG_SLOPE 0.2f
#define CHUNK 4096           // edges per block in bucket passes (782 blocks)
#define RMAX 2048            // max buckets supported by LDS hist

using frag_ab = __attribute__((ext_vector_type(8))) short;   // 8 bf16
using frag_cd = __attribute__((ext_vector_type(4))) float;   // 4 fp32

__device__ __forceinline__ float lrelu(float x) {
    return x >= 0.0f ? x : NEG_SLOPE * x;
}

__device__ __forceinline__ unsigned short f2bf(float f) {
    unsigned int u = __float_as_uint(f);
    unsigned int r = (u + 0x7fffu + ((u >> 16) & 1u)) >> 16;   // RNE
    return (unsigned short)r;
}
__device__ __forceinline__ float bflo(unsigned int p) {
    return __uint_as_float(p << 16);
}
__device__ __forceinline__ float bfhi(unsigned int p) {
    return __uint_as_float(p & 0xffff0000u);
}

// ---------------------------------------------------------------------------
// Weight prep: Wfc/Wres fp32 [64][256] -> Bf bf16 in MFMA B-frag lane order.
// ---------------------------------------------------------------------------
__global__ __launch_bounds__(256) void wprep_kernel(
    const float* __restrict__ Wfc, const float* __restrict__ Wres,
    unsigned short* __restrict__ Bf)
{
    int tid = blockIdx.x * 256 + threadIdx.x;   // 0..4095
    int ct = tid >> 9;
    int lane = tid & 63;
    int ks = (tid >> 6) & 7;
    int col = ct * 16 + (lane & 15);
    int kbase = ks * 32 + (lane >> 4) * 8;
    const float* srcW = (col < 64) ? (Wfc + (size_t)col * 256 + kbase)
                                   : (Wres + (size_t)(col - 64) * 256 + kbase);
    unsigned short* dstp = Bf + (size_t)tid * 8;
#pragma unroll
    for (int i = 0; i < 8; ++i) dstp[i] = f2bf(srcW[i]);
}

// ---------------------------------------------------------------------------
// MFMA projection: block = 256 threads (4 waves), 64 nodes.
// ---------------------------------------------------------------------------
__global__ __launch_bounds__(256) void proj_mfma_kernel(
    const float* __restrict__ feat, const unsigned short* __restrict__ Bf,
    const float* __restrict__ attn_l, const float* __restrict__ attn_r,
    unsigned short* __restrict__ fsb, float* __restrict__ el,
    float* __restrict__ er, float* __restrict__ out,
    float* __restrict__ denom_zero, int N)
{
    __shared__ __align__(16) unsigned short sA[64 * 280];   // 35840 B
    const int t = threadIdx.x;
    const int lane = t & 63;
    const int w = t >> 6;
    const int n0 = blockIdx.x * 64;
    if (n0 >= N) return;

    frag_ab bfrag[2][8];
    {
        const unsigned short* bp = Bf + (size_t)lane * 8;
#pragma unroll
        for (int j = 0; j < 2; ++j)
#pragma unroll
            for (int ks = 0; ks < 8; ++ks)
                bfrag[j][ks] = *(const frag_ab*)(bp + (size_t)((2 * w + j) * 8 + ks) * 512);
    }

    if (denom_zero && n0 * 4 + t < N * 4) denom_zero[n0 * 4 + t] = 0.0f;

    for (int i = 0; i < 8; ++i) {
        int f = i * 256 + t;
        int row = f >> 5, c8 = f & 31;
        int n = n0 + row;
        float4 v0 = make_float4(0.f, 0.f, 0.f, 0.f), v1 = v0;
        if (n < N) {
            const float4* p = (const float4*)(feat + (size_t)n * F_IN + c8 * 8);
            v0 = p[0]; v1 = p[1];
        }
        frag_ab pack;
        pack[0] = (short)f2bf(v0.x); pack[1] = (short)f2bf(v0.y);
        pack[2] = (short)f2bf(v0.z); pack[3] = (short)f2bf(v0.w);
        pack[4] = (short)f2bf(v1.x); pack[5] = (short)f2bf(v1.y);
        pack[6] = (short)f2bf(v1.z); pack[7] = (short)f2bf(v1.w);
        *(frag_ab*)(&sA[row * 280 + c8 * 8]) = pack;
    }
    __syncthreads();

    frag_cd acc[4][2];
#pragma unroll
    for (int rt = 0; rt < 4; ++rt)
#pragma unroll
        for (int j = 0; j < 2; ++j)
            acc[rt][j] = (frag_cd){0.f, 0.f, 0.f, 0.f};

#pragma unroll
    for (int ks = 0; ks < 8; ++ks) {
        frag_ab af[4];
#pragma unroll
        for (int rt = 0; rt < 4; ++rt) {
            int row = rt * 16 + (lane & 15);
            int c8 = ks * 4 + (lane >> 4);
            af[rt] = *(const frag_ab*)(&sA[row * 280 + c8 * 8]);
        }
#pragma unroll
        for (int rt = 0; rt < 4; ++rt)
#pragma unroll
            for (int j = 0; j < 2; ++j)
                acc[rt][j] = __builtin_amdgcn_mfma_f32_16x16x32_bf16(
                    af[rt], bfrag[j][ks], acc[rt][j], 0, 0, 0);
    }

    // epilogue: C/D layout col = lane&15, row = (lane>>4)*4 + reg  [m89]
    const int colq = lane & 15;
    const int quad = lane >> 4;
    if (w < 2) {
#pragma unroll
        for (int j = 0; j < 2; ++j) {
            int h = 2 * w + j;
            float al = attn_l[h * 16 + colq];
            float ar = attn_r[h * 16 + colq];
#pragma unroll
            for (int rt = 0; rt < 4; ++rt)
#pragma unroll
                for (int r = 0; r < 4; ++r) {
                    int node = n0 + rt * 16 + quad * 4 + r;
                    float v = acc[rt][j][r];
                    if (node < N) fsb[(size_t)node * O_OUT + h * 16 + colq] = f2bf(v);
                    float pl = v * al, pr = v * ar;
                    pl += __shfl_xor(pl, 1); pr += __shfl_xor(pr, 1);
                    pl += __shfl_xor(pl, 2); pr += __shfl_xor(pr, 2);
                    pl += __shfl_xor(pl, 4); pr += __shfl_xor(pr, 4);
                    pl += __shfl_xor(pl, 8); pr += __shfl_xor(pr, 8);
                    if (colq == 0 && node < N) {
                        el[(size_t)node * 4 + h] = pl;
                        er[(size_t)node * 4 + h] = pr;
                    }
                }
        }
    } else {
#pragma unroll
        for (int j = 0; j < 2; ++j) {
            int cb = 32 * (w - 2) + 16 * j;
#pragma unroll
            for (int rt = 0; rt < 4; ++rt)
#pragma unroll
                for (int r = 0; r < 4; ++r) {
                    int node = n0 + rt * 16 + quad * 4 + r;
                    if (node < N)
                        out[(size_t)node * O_OUT + cb + colq] = acc[rt][j][r];
                }
        }
    }
}

// ---------------------------------------------------------------------------
// Bucket pass A: per-block LDS histogram of dst>>7 -> histT[bin*B + b].
// ---------------------------------------------------------------------------
__global__ __launch_bounds__(256) void bucket_count_kernel(
    const int* __restrict__ dst, int* __restrict__ histT, int E, int B, int R)
{
    __shared__ int h[RMAX];
    int b = blockIdx.x, t = threadIdx.x;
    for (int i = t; i < R; i += 256) h[i] = 0;
    __syncthreads();
    int base = b * CHUNK;
    for (int i = t; i < CHUNK; i += 256) {
        int e = base + i;
        if (e < E) atomicAdd(&h[dst[e] >> 7], 1);
    }
    __syncthreads();
    for (int i = t; i < R; i += 256) histT[(size_t)i * B + b] = h[i];
}

// ---------------------------------------------------------------------------
// Scan chain (exclusive prefix sum over arbitrary n, 1024/block).
// ---------------------------------------------------------------------------
__global__ __launch_bounds__(256) void scan_block_kernel(
    const int* __restrict__ counts, int* __restrict__ outp,
    int* __restrict__ bsums, int n)
{
    int t = threadIdx.x;
    int base = blockIdx.x * 1024 + t * 4;
    int c0 = 0, c1 = 0, c2 = 0, c3 = 0;
    if (base + 3 < n) {
        int4 v = *(const int4*)(counts + base);
        c0 = v.x; c1 = v.y; c2 = v.z; c3 = v.w;
    } else {
        if (base     < n) c0 = counts[base];
        if (base + 1 < n) c1 = counts[base + 1];
        if (base + 2 < n) c2 = counts[base + 2];
        if (base + 3 < n) c3 = counts[base + 3];
    }
    int tsum = c0 + c1 + c2 + c3;
    int inc = tsum;
    int lane = t & 63, wid = t >> 6;
#pragma unroll
    for (int o = 1; o < 64; o <<= 1) {
        int v = __shfl_up(inc, o);
        if (lane >= o) inc += v;
    }
    __shared__ int wsum[4];
    if (lane == 63) wsum[wid] = inc;
    __syncthreads();
    int woff = 0;
#pragma unroll
    for (int w = 0; w < 4; ++w)
        if (w < wid) woff += wsum[w];
    int excl = woff + inc - tsum;
    int e0 = excl, e1 = excl + c0, e2 = e1 + c1, e3 = e2 + c2;
    if (base + 3 < n) {
        *(int4*)(outp + base) = make_int4(e0, e1, e2, e3);
    } else {
        if (base     < n) outp[base]     = e0;
        if (base + 1 < n) outp[base + 1] = e1;
        if (base + 2 < n) outp[base + 2] = e2;
        if (base + 3 < n) outp[base + 3] = e3;
    }
    if (t == 255) bsums[blockIdx.x] = wsum[0] + wsum[1] + wsum[2] + wsum[3];
}

__global__ void scan_bsums_kernel(int* __restrict__ bsums, int nb)
{
    int lane = threadIdx.x;   // 64 threads
    int carry = 0;
    for (int c = 0; c * 64 < nb; ++c) {
        int i = c * 64 + lane;
        int v = (i < nb) ? bsums[i] : 0;
        int inc = v;
#pragma unroll
        for (int o = 1; o < 64; o <<= 1) {
            int u = __shfl_up(inc, o);
            if (lane >= o) inc += u;
        }
        if (i < nb) bsums[i] = carry + inc - v;
        carry += __shfl(inc, 63);
    }
}

__global__ __launch_bounds__(256) void scan_final_kernel(
    int* __restrict__ outp, const int* __restrict__ bsums, int n, int total)
{
    int i = blockIdx.x * 256 + threadIdx.x;
    if (i < n) outp[i] = outp[i] + bsums[i >> 10];
    if (i == 0) outp[n] = total;   // outp must have n+1 capacity
}

// ---------------------------------------------------------------------------
// Bucket pass C: LDS-atomic local rank; write packed (src<<7)|dstlow to
// sorted_pk at histS[bin*B+b] + rank. Per-bucket runs are contiguous.
// ---------------------------------------------------------------------------
__global__ __launch_bounds__(256) void bucket_scatter_kernel(
    const int* __restrict__ src, const int* __restrict__ dst,
    const int* __restrict__ histS, unsigned int* __restrict__ sorted_pk,
    int E, int B, int R)
{
    __shared__ int h[RMAX];
    __shared__ int basebin[RMAX];
    int b = blockIdx.x, t = threadIdx.x;
    for (int i = t; i < R; i += 256) {
        h[i] = 0;
        basebin[i] = histS[(size_t)i * B + b];
    }
    __syncthreads();
    int base = b * CHUNK;
    for (int i = t; i < CHUNK; i += 256) {
        int e = base + i;
        if (e < E) {
            int d = dst[e];
            int bin = d >> 7;
            int rk = atomicAdd(&h[bin], 1);
            sorted_pk[basebin[bin] + rk] =
                ((unsigned int)src[e] << 7) | (unsigned int)(d & 127);
        }
    }
}

// ---------------------------------------------------------------------------
// Merged build+agg: one block per bucket (128 dst, 512 threads / 8 waves).
// LDS hist/scan/bin of the bucket's contiguous sorted_pk run, then each
// wave runs agg_csr's verified 64-lane gather loop on 16 dst, src from LDS.
// ---------------------------------------------------------------------------
__global__ __launch_bounds__(512) void agg_bucket_kernel(
    const int* __restrict__ histS, const unsigned int* __restrict__ sorted_pk,
    const unsigned short* __restrict__ fsb, const float* __restrict__ el,
    const float* __restrict__ er, float* __restrict__ out,
    int N, int E, int B, int R)
{
    __shared__ int buf2[8192];                  // binned src values, 32 KiB
    __shared__ int hist[128], scn[128], cur[128];
    const int r = blockIdx.x;
    const int t = threadIdx.x;
    int start = histS[(size_t)r * B];
    int end = (r + 1 < R) ? histS[(size_t)(r + 1) * B] : E;
    if (start < 0) start = 0;
    if (end < start) end = start;
    if (end > E) end = E;                       // clamps: identity on correct data
    const int cnt = end - start;

    if (t < 128) { hist[t] = 0; cur[t] = 0; }
    __syncthreads();
    // pass 1: histogram over dstlow (coalesced global pk read, LDS int atomics)
    for (int i = t; i < cnt; i += 512)
        atomicAdd(&hist[sorted_pk[start + i] & 127], 1);
    __syncthreads();
    if (t < 128) scn[t] = hist[t];
    __syncthreads();
    for (int o = 1; o < 128; o <<= 1) {
        int v = 0;
        if (t < 128 && t >= o) v = scn[t - o];
        __syncthreads();
        if (t < 128) scn[t] += v;
        __syncthreads();
    }
    // pass 2: bin src values into LDS (scn inclusive; offset = scn - hist)
    const bool use_lds = (cnt <= 8192);
    if (use_lds) {
        for (int i = t; i < cnt; i += 512) {
            unsigned int pk = sorted_pk[start + i];
            int low = (int)(pk & 127u);
            int rk = atomicAdd(&cur[low], 1);
            buf2[(scn[low] - hist[low]) + rk] = (int)(pk >> 7);
        }
    }
    __syncthreads();

    // agg: wave w handles dst r*128 + w*16 + j, j=0..15 (agg_csr loop body)
    const int lane = t & 63;
    const int w = t >> 6;              // 0..7
    const int half = lane >> 5;
    const int c = lane & 31;           // channels 2c, 2c+1
    const int h = c >> 3;
    for (int j = 0; j < 16; ++j) {
        int dl = w * 16 + j;
        int d = r * 128 + dl;
        if (d >= N) break;             // dl increasing -> all later invalid too
        const int k0 = scn[dl] - hist[dl];
        const int k1 = scn[dl];
        const float erh = er[(size_t)d * 4 + h];
        float a0 = 0.f, a1 = 0.f, den = 0.f;
        if (use_lds) {
            int kb = k0;
            for (; kb + 8 <= k1; kb += 8) {
                int s0 = buf2[kb + half];
                int s1 = buf2[kb + 2 + half];
                int s2 = buf2[kb + 4 + half];
                int s3 = buf2[kb + 6 + half];
                float e0 = el[(size_t)s0 * 4 + h];
                float e1 = el[(size_t)s1 * 4 + h];
                float e2 = el[(size_t)s2 * 4 + h];
                float e3 = el[(size_t)s3 * 4 + h];
                unsigned int f0 = *(const unsigned int*)(fsb + (size_t)s0 * O_OUT + 2 * c);
                unsigned int f1 = *(const unsigned int*)(fsb + (size_t)s1 * O_OUT + 2 * c);
                unsigned int f2 = *(const unsigned int*)(fsb + (size_t)s2 * O_OUT + 2 * c);
                unsigned int f3 = *(const unsigned int*)(fsb + (size_t)s3 * O_OUT + 2 * c);
                float w0 = __expf(lrelu(e0 + erh));
                float w1 = __expf(lrelu(e1 + erh));
                float w2 = __expf(lrelu(e2 + erh));
                float w3 = __expf(lrelu(e3 + erh));
                a0 += w0 * bflo(f0); a1 += w0 * bfhi(f0); den += w0;
                a0 += w1 * bflo(f1); a1 += w1 * bfhi(f1); den += w1;
                a0 += w2 * bflo(f2); a1 += w2 * bfhi(f2); den += w2;
                a0 += w3 * bflo(f3); a1 += w3 * bfhi(f3); den += w3;
            }
            for (; kb < k1; kb += 2) {
                int ki = kb + half;
                if (ki < k1) {
                    int s = buf2[ki];
                    float wv = __expf(lrelu(el[(size_t)s * 4 + h] + erh));
                    unsigned int f = *(const unsigned int*)(fsb + (size_t)s * O_OUT + 2 * c);
                    a0 += wv * bflo(f); a1 += wv * bfhi(f); den += wv;
                }
            }
        } else {
            // fallback (cnt > 8192, not expected at bench sizes): filter scan
            for (int i2 = 0; i2 < cnt; i2 += 2) {
                int ki = i2 + half;
                if (ki < cnt) {
                    unsigned int pk = sorted_pk[start + ki];
                    if ((int)(pk & 127u) == dl) {
                        int s = (int)(pk >> 7);
                        float wv = __expf(lrelu(el[(size_t)s * 4 + h] + erh));
                        unsigned int f = *(const unsigned int*)(fsb + (size_t)s * O_OUT + 2 * c);
                        a0 += wv * bflo(f); a1 += wv * bfhi(f); den += wv;
                    }
                }
            }
        }
        a0 += __shfl_xor(a0, 32);
        a1 += __shfl_xor(a1, 32);
        den += __shfl_xor(den, 32);
        if (half == 0) {
            float inv = 1.0f / fmaxf(den, 1e-20f);
            float2* po = (float2*)(out + (size_t)d * O_OUT + 2 * c);
            float2 o = *po;
            o.x += a0 * inv;
            o.y += a1 * inv;
            *po = o;
        }
    }
}

// ---------------------------------------------------------------------------
// Fallback path (small ws): no-max softmax, atomics, bf16 fs.
// ---------------------------------------------------------------------------
__global__ __launch_bounds__(256) void edge_sum_kernel(
    const int* __restrict__ src, const int* __restrict__ dst,
    const float* __restrict__ el, const float* __restrict__ er,
    float* __restrict__ denom, int E)
{
    int e = blockIdx.x * 256 + threadIdx.x;
    if (e >= E) return;
    int s = src[e], d = dst[e];
    float4 l4 = ((const float4*)el)[s];
    float4 r4 = ((const float4*)er)[d];
    unsafeAtomicAdd(&denom[(size_t)d * 4 + 0], __expf(lrelu(l4.x + r4.x)));
    unsafeAtomicAdd(&denom[(size_t)d * 4 + 1], __expf(lrelu(l4.y + r4.y)));
    unsafeAtomicAdd(&denom[(size_t)d * 4 + 2], __expf(lrelu(l4.z + r4.z)));
    unsafeAtomicAdd(&denom[(size_t)d * 4 + 3], __expf(lrelu(l4.w + r4.w)));
}

__global__ __launch_bounds__(256) void agg_atomic_kernel(
    const int* __restrict__ src, const int* __restrict__ dst,
    const unsigned short* __restrict__ fsb, const float* __restrict__ el,
    const float* __restrict__ er, const float* __restrict__ denom,
    float* __restrict__ out, int E)
{
    const int lane = threadIdx.x & 63;
    const int wid = threadIdx.x >> 6;
    int e = blockIdx.x * 4 + wid;
    if (e >= E) return;
    int s = src[e], d = dst[e];
    int h = lane >> 4;
    float v = __expf(lrelu(el[(size_t)s * 4 + h] + er[(size_t)d * 4 + h]));
    float alpha = v / fmaxf(denom[(size_t)d * 4 + h], 1e-20f);
    float fval = __uint_as_float(((unsigned int)fsb[(size_t)s * O_OUT + lane]) << 16);
    unsafeAtomicAdd(&out[(size_t)d * O_OUT + lane], alpha * fval);
}

extern "C" void kernel_launch(void* const* d_in, const int* in_sizes, int n_in,
                              void* d_out, int out_size, void* d_ws, size_t ws_size,
                              hipStream_t stream) {
    const float* feat   = (const float*)d_in[0];
    const float* Wfc    = (const float*)d_in[1];
    const float* attn_l = (const float*)d_in[2];
    const float* attn_r = (const float*)d_in[3];
    const float* Wres   = (const float*)d_in[4];
    const int*   src    = (const int*)d_in[5];
    const int*   dst    = (const int*)d_in[6];

    const int N = in_sizes[0] / F_IN;     // 100000
    const int E = in_sizes[5];            // 3200000
    float* out = (float*)d_out;

    const int R = (N + 127) >> 7;                 // buckets of 128 nodes
    const int B = (E + CHUNK - 1) / CHUNK;        // blocks in bucket passes
    const int nRB = R * B;
    const int nsb = (nRB + 1023) / 1024;

    // layout: el | er | Bf | histT[nRB] | histS[nRB+8] | bsums[1024] |
    //         sorted_pk[E] | fsb
    float* el     = (float*)d_ws;
    float* er     = el + (size_t)N * 4;
    unsigned short* Bf = (unsigned short*)(er + (size_t)N * 4);
    int*   histT  = (int*)(Bf + 32768);
    int*   histS  = histT + nRB;
    int*   bsums  = histS + nRB + 8;
    unsigned int* sorted_pk = (unsigned int*)(bsums + 1024);
    unsigned short* fsb = (unsigned short*)(sorted_pk + E);
    size_t need_main = (size_t)((char*)(fsb + (size_t)N * O_OUT) - (char*)d_ws);

    int nproj = (N + 63) / 64;

    if (ws_size >= need_main && R <= RMAX && nsb <= 1024) {
        wprep_kernel<<<16, 256, 0, stream>>>(Wfc, Wres, Bf);
        proj_mfma_kernel<<<nproj, 256, 0, stream>>>(
            feat, Bf, attn_l, attn_r, fsb, el, er, out, nullptr, N);
        bucket_count_kernel<<<B, 256, 0, stream>>>(dst, histT, E, B, R);
        scan_block_kernel<<<nsb, 256, 0, stream>>>(histT, histS, bsums, nRB);
        scan_bsums_kernel<<<1, 64, 0, stream>>>(bsums, nsb);
        scan_final_kernel<<<(nRB + 255) / 256, 256, 0, stream>>>(histS, bsums, nRB, E);
        bucket_scatter_kernel<<<B, 256, 0, stream>>>(src, dst, histS, sorted_pk, E, B, R);
        agg_bucket_kernel<<<R, 512, 0, stream>>>(
            histS, sorted_pk, fsb, el, er, out, N, E, B, R);
    } else {
        // fallback: denom overlays histT region; fsb right after denom
        float* denom = (float*)histT;                 // [N*4]
        unsigned short* fsb2 = (unsigned short*)(denom + (size_t)N * 4);
        wprep_kernel<<<16, 256, 0, stream>>>(Wfc, Wres, Bf);
        proj_mfma_kernel<<<nproj, 256, 0, stream>>>(
            feat, Bf, attn_l, attn_r, fsb2, el, er, out, denom, N);
        edge_sum_kernel<<<(E + 255) / 256, 256, 0, stream>>>(src, dst, el, er, denom, E);
        agg_atomic_kernel<<<(E + 3) / 4, 256, 0, stream>>>(
            src, dst, fsb2, el, er, denom, out, E);
    }
}